// Round 1
// baseline (914.516 us; speedup 1.0000x reference)
//
#include <hip/hip_runtime.h>
#include <cmath>

// ---------------------------------------------------------------------------
// 3-layer GCN, fp32. Pipeline per layer: GEMM (dense, 64->64/47) -> zero agg
// -> edge scatter-add (unsafeAtomicAdd) ; bias+ReLU fused into next GEMM's
// input load. Final: wave-per-node log_softmax over 47 classes.
// Workspace: tmp[N*64] + agg[N*64] = 51.2 MB.
// ---------------------------------------------------------------------------

__device__ __forceinline__ float wave_max64(float v) {
#pragma unroll
  for (int off = 32; off >= 1; off >>= 1)
    v = fmaxf(v, __shfl_xor(v, off, 64));
  return v;
}

__device__ __forceinline__ float wave_sum64(float v) {
#pragma unroll
  for (int off = 32; off >= 1; off >>= 1)
    v += __shfl_xor(v, off, 64);
  return v;
}

// out[r][j] = dot(f(in[r][:]), W[:][j]); f = relu(x + b) when BRELU.
// One wave per row; lane j owns output column j; W column in 64 VGPRs;
// x-row read as wave-uniform float4 broadcasts (L1-hot after first touch).
template <int DOUT, bool BRELU>
__launch_bounds__(256)
__global__ void gemm_k(const float* __restrict__ in, const float* __restrict__ Wm,
                       const float* __restrict__ bin, float* __restrict__ out, int n) {
  const int lane = threadIdx.x & 63;
  const int wave = (int)((blockIdx.x * blockDim.x + threadIdx.x) >> 6);
  const int nw   = (int)((gridDim.x * blockDim.x) >> 6);
  const int col  = lane < DOUT ? lane : DOUT - 1;

  float w[64];
#pragma unroll
  for (int k = 0; k < 64; ++k) w[k] = Wm[k * DOUT + col];

  float4 b4[16];
  if (BRELU) {
#pragma unroll
    for (int i = 0; i < 16; ++i) b4[i] = ((const float4*)bin)[i];
  }

  for (int r = wave; r < n; r += nw) {
    const float4* xr = (const float4*)(in + (size_t)r * 64);
    float acc = 0.f;
#pragma unroll
    for (int i = 0; i < 16; ++i) {
      float4 x4 = xr[i];
      if (BRELU) {
        x4.x = fmaxf(x4.x + b4[i].x, 0.f);
        x4.y = fmaxf(x4.y + b4[i].y, 0.f);
        x4.z = fmaxf(x4.z + b4[i].z, 0.f);
        x4.w = fmaxf(x4.w + b4[i].w, 0.f);
      }
      acc = fmaf(x4.x, w[4 * i + 0], acc);
      acc = fmaf(x4.y, w[4 * i + 1], acc);
      acc = fmaf(x4.z, w[4 * i + 2], acc);
      acc = fmaf(x4.w, w[4 * i + 3], acc);
    }
    if (lane < DOUT) out[(size_t)r * DOUT + lane] = acc;
  }
}

// One wave per edge: lane j moves feature j. Gather coalesced (256B/row),
// hardware fp32 atomics into the (L2/L3-resident) aggregate buffer.
template <int D>
__launch_bounds__(256)
__global__ void scatter_k(const float* __restrict__ msg, const int* __restrict__ srci,
                          const int* __restrict__ dsti, float* __restrict__ agg, int ne) {
  const int lane = threadIdx.x & 63;
  const int wave = (int)((blockIdx.x * blockDim.x + threadIdx.x) >> 6);
  const int nw   = (int)((gridDim.x * blockDim.x) >> 6);
  for (int e = wave; e < ne; e += nw) {
    const int s = srci[e];
    const int d = dsti[e];
    if (lane < D) {
      float v = msg[(size_t)s * D + lane];
      unsafeAtomicAdd(&agg[(size_t)d * D + lane], v);
    }
  }
}

// One wave per node: out = (agg + b) - max - log(sum exp(.-max)) over 47 classes.
__launch_bounds__(256)
__global__ void logsoftmax_k(const float* __restrict__ agg, const float* __restrict__ bias,
                             float* __restrict__ out, int n) {
  const int lane = threadIdx.x & 63;
  const int wave = (int)((blockIdx.x * blockDim.x + threadIdx.x) >> 6);
  const int nw   = (int)((gridDim.x * blockDim.x) >> 6);
  const float b  = lane < 47 ? bias[lane] : 0.f;
  for (int r = wave; r < n; r += nw) {
    float v  = lane < 47 ? agg[(size_t)r * 47 + lane] + b : -INFINITY;
    float m  = wave_max64(v);
    float ex = lane < 47 ? __expf(v - m) : 0.f;
    float s  = wave_sum64(ex);
    if (lane < 47) out[(size_t)r * 47 + lane] = v - m - __logf(s);
  }
}

extern "C" void kernel_launch(void* const* d_in, const int* in_sizes, int n_in,
                              void* d_out, int out_size, void* d_ws, size_t ws_size,
                              hipStream_t stream) {
  const float* x  = (const float*)d_in[0];
  const int*   ei = (const int*)d_in[1];   // [2, E] int32, row-major
  const float* W1 = (const float*)d_in[2];
  const float* b1 = (const float*)d_in[3];
  const float* W2 = (const float*)d_in[4];
  const float* b2 = (const float*)d_in[5];
  const float* W3 = (const float*)d_in[6];
  const float* b3 = (const float*)d_in[7];
  float* outp = (float*)d_out;

  const int n  = in_sizes[0] / 64;   // 100000 nodes
  const int ne = in_sizes[1] / 2;    // 800000 edges
  const int* srci = ei;
  const int* dsti = ei + ne;

  float* tmp = (float*)d_ws;                 // n*64 floats (also holds n*47)
  float* agg = tmp + (size_t)n * 64;         // n*64 floats

  const int TB = 256;
  const int gemm_blocks = (n + 3) / 4;   // 1 row / wave
  const int scat_blocks = 16384;         // ~12 edges / wave, grid-stride
  const int ls_blocks   = (n + 3) / 4;

  // ---- Layer 1: tmp = x @ W1 ; agg = scatter(tmp) ----
  gemm_k<64, false><<<gemm_blocks, TB, 0, stream>>>(x, W1, nullptr, tmp, n);
  hipMemsetAsync(agg, 0, (size_t)n * 64 * sizeof(float), stream);
  scatter_k<64><<<scat_blocks, TB, 0, stream>>>(tmp, srci, dsti, agg, ne);

  // ---- Layer 2: tmp = relu(agg + b1) @ W2 ; agg = scatter(tmp) ----
  gemm_k<64, true><<<gemm_blocks, TB, 0, stream>>>(agg, W2, b1, tmp, n);
  hipMemsetAsync(agg, 0, (size_t)n * 64 * sizeof(float), stream);
  scatter_k<64><<<scat_blocks, TB, 0, stream>>>(tmp, srci, dsti, agg, ne);

  // ---- Layer 3: tmp = relu(agg + b2) @ W3 ; agg = scatter(tmp) ----
  gemm_k<47, true><<<gemm_blocks, TB, 0, stream>>>(agg, W3, b2, tmp, n);
  hipMemsetAsync(agg, 0, (size_t)n * 47 * sizeof(float), stream);
  scatter_k<47><<<scat_blocks, TB, 0, stream>>>(tmp, srci, dsti, agg, ne);

  // ---- log_softmax(agg + b3) -> out ----
  logsoftmax_k<<<ls_blocks, TB, 0, stream>>>(agg, b3, outp, n);
}

// Round 2
// 515.732 us; speedup vs baseline: 1.7732x; 1.7732x over previous
//
#include <hip/hip_runtime.h>
#include <cmath>

// ---------------------------------------------------------------------------
// 3-layer GCN, fp32, atomic-free.
// Per call: build CSR of edges sorted by dst (hist -> scan -> fill), then
//   s1 = gather_reduce(x)        ; h1 = relu(s1@W1+b1)
//   s2 = gather_reduce(h1)       ; h2 = relu(s2@W2+b2)
//   s3 = gather_reduce(h2)       ; out = log_softmax(s3@W3+b3)   [fused]
// Uses linearity: segment_sum(h[src]) = segment_sum(x[src]) @ W.
// Workspace: 2 x N*64 float bufs (51.2MB) + CSR ints (~4.4MB).
// ---------------------------------------------------------------------------

#define SCAN_B 256

__device__ __forceinline__ float wave_max64(float v) {
#pragma unroll
  for (int off = 32; off >= 1; off >>= 1) v = fmaxf(v, __shfl_xor(v, off, 64));
  return v;
}
__device__ __forceinline__ float wave_sum64(float v) {
#pragma unroll
  for (int off = 32; off >= 1; off >>= 1) v += __shfl_xor(v, off, 64);
  return v;
}

__global__ void hist_k(const int* __restrict__ dsti, int* __restrict__ cnt, int ne) {
  int i = blockIdx.x * blockDim.x + threadIdx.x;
  int st = gridDim.x * blockDim.x;
  for (int e = i; e < ne; e += st) atomicAdd(&cnt[dsti[e]], 1);
}

// in-place per-block exclusive scan of cnt; block totals -> bsum
__global__ void scan1_k(int* __restrict__ cnt, int* __restrict__ bsum, int n) {
  __shared__ int sh[SCAN_B];
  int t = threadIdx.x, i = blockIdx.x * SCAN_B + t;
  int x = (i < n) ? cnt[i] : 0;
  sh[t] = x; __syncthreads();
  for (int o = 1; o < SCAN_B; o <<= 1) {
    int v = (t >= o) ? sh[t - o] : 0; __syncthreads();
    sh[t] += v; __syncthreads();
  }
  if (i < n) cnt[i] = sh[t] - x;           // exclusive within block
  if (t == SCAN_B - 1) bsum[blockIdx.x] = sh[t];
}

// single-block exclusive scan of block sums (nb <= 512)
__global__ void scan2_k(int* __restrict__ bsum, int nb) {
  __shared__ int sh[512];
  int t = threadIdx.x;
  int x = (t < nb) ? bsum[t] : 0;
  sh[t] = x; __syncthreads();
  for (int o = 1; o < 512; o <<= 1) {
    int v = (t >= o) ? sh[t - o] : 0; __syncthreads();
    sh[t] += v; __syncthreads();
  }
  if (t < nb) bsum[t] = sh[t] - x;
}

__global__ void scan3_k(const int* __restrict__ cnt, const int* __restrict__ bsum,
                        int* __restrict__ row_off, int* __restrict__ cursor, int n, int e) {
  int i = blockIdx.x * SCAN_B + threadIdx.x;
  if (i < n) {
    int v = cnt[i] + bsum[i / SCAN_B];
    row_off[i] = v; cursor[i] = v;
  }
  if (i == 0) row_off[n] = e;
}

__global__ void fill_k(const int* __restrict__ srci, const int* __restrict__ dsti,
                       int* __restrict__ cursor, int* __restrict__ ssrc, int ne) {
  int i = blockIdx.x * blockDim.x + threadIdx.x;
  int st = gridDim.x * blockDim.x;
  for (int e = i; e < ne; e += st) {
    int p = atomicAdd(&cursor[dsti[e]], 1);
    ssrc[p] = srci[e];
  }
}

// One wave per node: sum in[s][lane] over its CSR edge list, single write.
__launch_bounds__(256)
__global__ void gather_k(const float* __restrict__ in, const int* __restrict__ row_off,
                         const int* __restrict__ ssrc, float* __restrict__ outp, int n) {
  const int lane = threadIdx.x & 63;
  int wave = (int)((blockIdx.x * blockDim.x + threadIdx.x) >> 6);
  int nw   = (int)((gridDim.x * blockDim.x) >> 6);
  for (int v = wave; v < n; v += nw) {
    const int start = row_off[v], end = row_off[v + 1];
    float a0 = 0.f, a1 = 0.f, a2 = 0.f, a3 = 0.f;
    for (int c = start; c < end; c += 64) {
      const int m  = min(64, end - c);
      const int sv = (c + lane < end) ? ssrc[c + lane] : 0;
      int j = 0;
      for (; j + 3 < m; j += 4) {
        int s0 = __shfl(sv, j, 64), s1 = __shfl(sv, j + 1, 64);
        int s2 = __shfl(sv, j + 2, 64), s3 = __shfl(sv, j + 3, 64);
        a0 += in[(size_t)s0 * 64 + lane];
        a1 += in[(size_t)s1 * 64 + lane];
        a2 += in[(size_t)s2 * 64 + lane];
        a3 += in[(size_t)s3 * 64 + lane];
      }
      for (; j < m; ++j) a0 += in[(size_t)__shfl(sv, j, 64) * 64 + lane];
    }
    outp[(size_t)v * 64 + lane] = (a0 + a1) + (a2 + a3);
  }
}

// out[r][lane] = relu(dot(in[r], W[:,lane]) + b[lane]); 2 rows/wave for ILP.
__launch_bounds__(256)
__global__ void gemm64_k(const float* __restrict__ in, const float* __restrict__ Wm,
                         const float* __restrict__ bin, float* __restrict__ outp, int n) {
  const int lane = threadIdx.x & 63;
  int wave = (int)((blockIdx.x * blockDim.x + threadIdx.x) >> 6);
  int nw   = (int)((gridDim.x * blockDim.x) >> 6);
  float w[64];
#pragma unroll
  for (int k = 0; k < 64; ++k) w[k] = Wm[k * 64 + lane];
  const float b = bin[lane];
  for (int r0 = wave * 2; r0 < n; r0 += nw * 2) {
    const bool has1 = (r0 + 1) < n;
    const float4* x0 = (const float4*)(in + (size_t)r0 * 64);
    const float4* x1 = (const float4*)(in + (size_t)(has1 ? r0 + 1 : r0) * 64);
    float acc0 = 0.f, acc1 = 0.f;
#pragma unroll
    for (int i = 0; i < 16; ++i) {
      float4 p = x0[i], q = x1[i];
      acc0 = fmaf(p.x, w[4 * i + 0], acc0); acc1 = fmaf(q.x, w[4 * i + 0], acc1);
      acc0 = fmaf(p.y, w[4 * i + 1], acc0); acc1 = fmaf(q.y, w[4 * i + 1], acc1);
      acc0 = fmaf(p.z, w[4 * i + 2], acc0); acc1 = fmaf(q.z, w[4 * i + 2], acc1);
      acc0 = fmaf(p.w, w[4 * i + 3], acc0); acc1 = fmaf(q.w, w[4 * i + 3], acc1);
    }
    outp[(size_t)r0 * 64 + lane] = fmaxf(acc0 + b, 0.f);
    if (has1) outp[(size_t)(r0 + 1) * 64 + lane] = fmaxf(acc1 + b, 0.f);
  }
}

// Final layer: 47-col GEMM + bias + log_softmax fused; one wave per row.
__launch_bounds__(256)
__global__ void gemm_ls_k(const float* __restrict__ in, const float* __restrict__ Wm,
                          const float* __restrict__ bin, float* __restrict__ outp, int n) {
  const int lane = threadIdx.x & 63;
  const int col  = lane < 47 ? lane : 46;
  int wave = (int)((blockIdx.x * blockDim.x + threadIdx.x) >> 6);
  int nw   = (int)((gridDim.x * blockDim.x) >> 6);
  float w[64];
#pragma unroll
  for (int k = 0; k < 64; ++k) w[k] = Wm[k * 47 + col];
  const float b = bin[col];
  for (int r = wave; r < n; r += nw) {
    const float4* xr = (const float4*)(in + (size_t)r * 64);
    float acc = 0.f;
#pragma unroll
    for (int i = 0; i < 16; ++i) {
      float4 p = xr[i];
      acc = fmaf(p.x, w[4 * i + 0], acc);
      acc = fmaf(p.y, w[4 * i + 1], acc);
      acc = fmaf(p.z, w[4 * i + 2], acc);
      acc = fmaf(p.w, w[4 * i + 3], acc);
    }
    float v  = lane < 47 ? acc + b : -INFINITY;
    float m  = wave_max64(v);
    float ex = lane < 47 ? __expf(v - m) : 0.f;
    float s  = wave_sum64(ex);
    if (lane < 47) outp[(size_t)r * 47 + lane] = v - m - __logf(s);
  }
}

extern "C" void kernel_launch(void* const* d_in, const int* in_sizes, int n_in,
                              void* d_out, int out_size, void* d_ws, size_t ws_size,
                              hipStream_t stream) {
  const float* x  = (const float*)d_in[0];
  const int*   ei = (const int*)d_in[1];   // [2, E] int32, row-major
  const float* W1 = (const float*)d_in[2];
  const float* b1 = (const float*)d_in[3];
  const float* W2 = (const float*)d_in[4];
  const float* b2 = (const float*)d_in[5];
  const float* W3 = (const float*)d_in[6];
  const float* b3 = (const float*)d_in[7];
  float* outp = (float*)d_out;

  const int n  = in_sizes[0] / 64;   // 100000
  const int ne = in_sizes[1] / 2;    // 800000
  const int* srci = ei;
  const int* dsti = ei + ne;

  const size_t N64 = (size_t)n * 64;
  float* bufA   = (float*)d_ws;            // N*64
  float* bufB   = bufA + N64;              // N*64
  int* cnt      = (int*)(bufB + N64);      // N   (becomes per-block-exclusive scan)
  int* row_off  = cnt + n;                 // N+1
  int* cursor   = row_off + n + 1;         // N
  int* bsum     = cursor + n;              // 512
  int* ssrc     = bsum + 512;              // E

  const int TB = 256;
  const int nscan = (n + SCAN_B - 1) / SCAN_B;       // 391
  const int eblocks = (ne + TB - 1) / TB;            // 3125
  const int gat_blocks = (n + 3) / 4;                // 1 wave/node
  const int gem_blocks = (n + 7) / 8;                // 2 rows/wave

  // ---- CSR build (per call; d_ws is re-poisoned) ----
  hipMemsetAsync(cnt, 0, (size_t)n * sizeof(int), stream);
  hist_k<<<eblocks, TB, 0, stream>>>(dsti, cnt, ne);
  scan1_k<<<nscan, SCAN_B, 0, stream>>>(cnt, bsum, n);
  scan2_k<<<1, 512, 0, stream>>>(bsum, nscan);
  scan3_k<<<nscan, SCAN_B, 0, stream>>>(cnt, bsum, row_off, cursor, n, ne);
  fill_k<<<eblocks, TB, 0, stream>>>(srci, dsti, cursor, ssrc, ne);

  // ---- Layer 1 ----
  gather_k<<<gat_blocks, TB, 0, stream>>>(x, row_off, ssrc, bufA, n);
  gemm64_k<<<gem_blocks, TB, 0, stream>>>(bufA, W1, b1, bufB, n);
  // ---- Layer 2 ----
  gather_k<<<gat_blocks, TB, 0, stream>>>(bufB, row_off, ssrc, bufA, n);
  gemm64_k<<<gem_blocks, TB, 0, stream>>>(bufA, W2, b2, bufB, n);
  // ---- Layer 3 + log_softmax ----
  gather_k<<<gat_blocks, TB, 0, stream>>>(bufB, row_off, ssrc, bufA, n);
  gemm_ls_k<<<gat_blocks, TB, 0, stream>>>(bufA, W3, b3, outp, n);
}

// Round 3
// 395.638 us; speedup vs baseline: 2.3115x; 1.3035x over previous
//
#include <hip/hip_runtime.h>
#include <cmath>

// ---------------------------------------------------------------------------
// 3-layer GCN, fp32, atomic-free, fully fused per layer.
// Per call: build CSR of edges sorted by dst (hist -> scan -> fill), then
//   h1  = relu(gather(x) @W1 + b1)          [one kernel]
//   h2  = relu(gather(h1)@W2 + b2)          [one kernel]
//   out = log_softmax(gather(h2)@W3 + b3)   [one kernel]
// (linearity: segment_sum(h[src]) = segment_sum(x[src]) @ W)
// Gather: 1 wave/node, 4 edges x float4/lane per load, 2-deep unrolled.
// GEMM epilogue: butterfly-reduce -> wave-private LDS row -> per-lane W
// column held in 64 pinned VGPRs.
// ---------------------------------------------------------------------------

#define SCAN_B 256

__device__ __forceinline__ float wave_max64(float v) {
#pragma unroll
  for (int off = 32; off >= 1; off >>= 1) v = fmaxf(v, __shfl_xor(v, off, 64));
  return v;
}
__device__ __forceinline__ float wave_sum64(float v) {
#pragma unroll
  for (int off = 32; off >= 1; off >>= 1) v += __shfl_xor(v, off, 64);
  return v;
}

// ---------------- CSR build ----------------
__global__ void hist_k(const int* __restrict__ dsti, int* __restrict__ cnt, int ne) {
  int i = blockIdx.x * blockDim.x + threadIdx.x;
  int st = gridDim.x * blockDim.x;
  for (int e = i; e < ne; e += st) atomicAdd(&cnt[dsti[e]], 1);
}

__global__ void scan1_k(int* __restrict__ cnt, int* __restrict__ bsum, int n) {
  __shared__ int sh[SCAN_B];
  int t = threadIdx.x, i = blockIdx.x * SCAN_B + t;
  int x = (i < n) ? cnt[i] : 0;
  sh[t] = x; __syncthreads();
  for (int o = 1; o < SCAN_B; o <<= 1) {
    int v = (t >= o) ? sh[t - o] : 0; __syncthreads();
    sh[t] += v; __syncthreads();
  }
  if (i < n) cnt[i] = sh[t] - x;
  if (t == SCAN_B - 1) bsum[blockIdx.x] = sh[t];
}

__global__ void scan2_k(int* __restrict__ bsum, int nb) {
  __shared__ int sh[512];
  int t = threadIdx.x;
  int x = (t < nb) ? bsum[t] : 0;
  sh[t] = x; __syncthreads();
  for (int o = 1; o < 512; o <<= 1) {
    int v = (t >= o) ? sh[t - o] : 0; __syncthreads();
    sh[t] += v; __syncthreads();
  }
  if (t < nb) bsum[t] = sh[t] - x;
}

__global__ void scan3_k(const int* __restrict__ cnt, const int* __restrict__ bsum,
                        int* __restrict__ row_off, int* __restrict__ cursor, int n, int e) {
  int i = blockIdx.x * SCAN_B + threadIdx.x;
  if (i < n) {
    int v = cnt[i] + bsum[i / SCAN_B];
    row_off[i] = v; cursor[i] = v;
  }
  if (i == 0) row_off[n] = e;
}

__global__ void fill_k(const int* __restrict__ srci, const int* __restrict__ dsti,
                       int* __restrict__ cursor, int* __restrict__ ssrc, int ne) {
  int i = blockIdx.x * blockDim.x + threadIdx.x;
  int st = gridDim.x * blockDim.x;
  for (int e = i; e < ne; e += st) {
    int p = atomicAdd(&cursor[dsti[e]], 1);
    ssrc[p] = srci[e];
  }
}

// ---------------- fused gather + GEMM (+relu | +log_softmax) ----------------
// One wave per node. Lane layout for gather: eg = lane>>4 (edge slot 0..3),
// f = lane&15 (float4 feature group). Epilogue: lane = output column.
template <int DOUT, bool LS>
__launch_bounds__(256)
__global__ void fused_gcn_k(const float* __restrict__ in, const int* __restrict__ row_off,
                            const int* __restrict__ ssrc, const float* __restrict__ Wm,
                            const float* __restrict__ bin, float* __restrict__ outp, int n) {
  const int lane  = threadIdx.x & 63;
  const int wslot = threadIdx.x >> 6;          // wave within block (0..3)
  const int eg    = lane >> 4;                 // edge slot
  const int f     = lane & 15;                 // feature float4 group
  const int col   = lane < DOUT ? lane : DOUT - 1;

  // W column in 64 pinned VGPRs (asm "+v" prevents rematerializing loads).
  float w[64];
#pragma unroll
  for (int k = 0; k < 64; ++k) w[k] = Wm[k * DOUT + col];
#pragma unroll
  for (int k = 0; k < 64; ++k) asm volatile("" : "+v"(w[k]));
  const float bcol = bin[col];

  __shared__ float4 sbuf[4 * 16];              // one 64-float row per wave

  const float4* in4 = (const float4*)in;
  int wave = (int)((blockIdx.x * blockDim.x + threadIdx.x) >> 6);
  int nw   = (int)((gridDim.x * blockDim.x) >> 6);

  for (int v = wave; v < n; v += nw) {
    const int start = row_off[v], end = row_off[v + 1];
    float4 a0 = make_float4(0.f, 0.f, 0.f, 0.f);
    float4 a1 = make_float4(0.f, 0.f, 0.f, 0.f);
    for (int c = start; c < end; c += 8) {
      const int e0 = c + eg, e1 = e0 + 4;
      if (e0 < end) {
        const int s = ssrc[e0];
        float4 t = in4[(size_t)s * 16 + f];
        a0.x += t.x; a0.y += t.y; a0.z += t.z; a0.w += t.w;
      }
      if (e1 < end) {
        const int s = ssrc[e1];
        float4 t = in4[(size_t)s * 16 + f];
        a1.x += t.x; a1.y += t.y; a1.z += t.z; a1.w += t.w;
      }
    }
    float4 a = make_float4(a0.x + a1.x, a0.y + a1.y, a0.z + a1.z, a0.w + a1.w);
    // butterfly across the 4 edge slots -> every lane holds full sum of group f
#pragma unroll
    for (int off = 16; off <= 32; off <<= 1) {
      a.x += __shfl_xor(a.x, off, 64);
      a.y += __shfl_xor(a.y, off, 64);
      a.z += __shfl_xor(a.z, off, 64);
      a.w += __shfl_xor(a.w, off, 64);
    }
    // wave-private LDS row (same-wave write->read, in-order DS pipeline)
    if (lane < 16) sbuf[wslot * 16 + lane] = a;
    float dot = bcol;
#pragma unroll
    for (int k4 = 0; k4 < 16; ++k4) {
      const float4 s4 = sbuf[wslot * 16 + k4];   // wave-uniform broadcast read
      dot = fmaf(s4.x, w[4 * k4 + 0], dot);
      dot = fmaf(s4.y, w[4 * k4 + 1], dot);
      dot = fmaf(s4.z, w[4 * k4 + 2], dot);
      dot = fmaf(s4.w, w[4 * k4 + 3], dot);
    }
    if (!LS) {
      outp[(size_t)v * 64 + lane] = fmaxf(dot, 0.f);
    } else {
      float val = lane < DOUT ? dot : -INFINITY;
      float m   = wave_max64(val);
      float ex  = lane < DOUT ? __expf(val - m) : 0.f;
      float s   = wave_sum64(ex);
      if (lane < DOUT) outp[(size_t)v * DOUT + lane] = val - m - __logf(s);
    }
  }
}

extern "C" void kernel_launch(void* const* d_in, const int* in_sizes, int n_in,
                              void* d_out, int out_size, void* d_ws, size_t ws_size,
                              hipStream_t stream) {
  const float* x  = (const float*)d_in[0];
  const int*   ei = (const int*)d_in[1];   // [2, E] int32, row-major
  const float* W1 = (const float*)d_in[2];
  const float* b1 = (const float*)d_in[3];
  const float* W2 = (const float*)d_in[4];
  const float* b2 = (const float*)d_in[5];
  const float* W3 = (const float*)d_in[6];
  const float* b3 = (const float*)d_in[7];
  float* outp = (float*)d_out;

  const int n  = in_sizes[0] / 64;   // 100000
  const int ne = in_sizes[1] / 2;    // 800000
  const int* srci = ei;
  const int* dsti = ei + ne;

  const size_t N64 = (size_t)n * 64;
  float* bufA   = (float*)d_ws;            // N*64 (h1)
  float* bufB   = bufA + N64;              // N*64 (h2)
  int* cnt      = (int*)(bufB + N64);      // N
  int* row_off  = cnt + n;                 // N+1
  int* cursor   = row_off + n + 1;         // N
  int* bsum     = cursor + n;              // 512
  int* ssrc     = bsum + 512;              // E

  const int TB = 256;
  const int nscan = (n + SCAN_B - 1) / SCAN_B;
  const int eblocks = (ne + TB - 1) / TB;
  const int fus_blocks = 4096;             // grid-stride, ~6 nodes/wave

  // ---- CSR build (per call; d_ws is re-poisoned) ----
  hipMemsetAsync(cnt, 0, (size_t)n * sizeof(int), stream);
  hist_k<<<eblocks, TB, 0, stream>>>(dsti, cnt, ne);
  scan1_k<<<nscan, SCAN_B, 0, stream>>>(cnt, bsum, n);
  scan2_k<<<1, 512, 0, stream>>>(bsum, nscan);
  scan3_k<<<nscan, SCAN_B, 0, stream>>>(cnt, bsum, row_off, cursor, n, ne);
  fill_k<<<eblocks, TB, 0, stream>>>(srci, dsti, cursor, ssrc, ne);

  // ---- fused layers ----
  fused_gcn_k<64, false><<<fus_blocks, TB, 0, stream>>>(x,    row_off, ssrc, W1, b1, bufA, n);
  fused_gcn_k<64, false><<<fus_blocks, TB, 0, stream>>>(bufA, row_off, ssrc, W2, b2, bufB, n);
  fused_gcn_k<47, true ><<<fus_blocks, TB, 0, stream>>>(bufB, row_off, ssrc, W3, b3, outp, n);
}